// Round 5
// baseline (701.249 us; speedup 1.0000x reference)
//
#include <hip/hip_runtime.h>

// Fused: proj(QKV) -> 4-head attention (S=32, D=32) -> out-proj -> residual -> LayerNorm
// B=16384 batch rows, each [S=32, E=128]. One block (4 waves) per batch row; wave w = head w.
// bf16 MFMA (16x16x32) with f32 accumulation; residual + LN stats in f32.

typedef __attribute__((ext_vector_type(8))) short bfrag;   // 8 bf16 = 4 VGPRs (MFMA A/B operand)
typedef __attribute__((ext_vector_type(4))) short sh4;     // 4 bf16 = 8B
typedef __attribute__((ext_vector_type(4))) float f32x4;   // MFMA C/D operand

#define NBLK 512
#define NB_PER_BLK 32   // 512 * 32 = 16384 batch rows

__device__ __forceinline__ unsigned short f2bf(float x) {  // f32 -> bf16, round-to-nearest-even
  union { float f; unsigned u; } v; v.f = x;
  unsigned r = v.u + 0x7FFFu + ((v.u >> 16) & 1u);
  return (unsigned short)(r >> 16);
}

__device__ __forceinline__ bfrag pack8(const float4 a, const float4 b) {
  bfrag o;
  o[0] = (short)f2bf(a.x); o[1] = (short)f2bf(a.y); o[2] = (short)f2bf(a.z); o[3] = (short)f2bf(a.w);
  o[4] = (short)f2bf(b.x); o[5] = (short)f2bf(b.y); o[6] = (short)f2bf(b.z); o[7] = (short)f2bf(b.w);
  return o;
}

__global__ __launch_bounds__(256, 2) void fused_sa_kernel(
    const float* __restrict__ xin,
    const float* __restrict__ Wq, const float* __restrict__ bq,
    const float* __restrict__ Wk, const float* __restrict__ bk,
    const float* __restrict__ Wv, const float* __restrict__ bv,
    const float* __restrict__ Wo, const float* __restrict__ bo,
    const float* __restrict__ gam, const float* __restrict__ bet,
    float* __restrict__ out)
{
  // LDS: 8192 + 16896 + 3*10240 + 8704 + 1024 = 65536 B -> 2 blocks/CU
  __shared__ unsigned short xbf[32 * 128];      // bf16 x, XOR-swizzled rows (A-frag source)
  __shared__ float          xf[32 * 132];       // f32 x, padded stride (residual)
  __shared__ unsigned short qpb[4][32 * 40];    // per-wave Q, later P   (row-major, pad->40)
  __shared__ unsigned short kbuf[4][32 * 40];   // per-wave K
  __shared__ unsigned short vtb[4][32 * 40];    // per-wave V^T
  __shared__ unsigned short ctxb[32 * 136];     // ctx [32][128+8] bf16
  __shared__ float          redb[4][32][2];     // LN partials (sum, sumsq) per wave per row

  const int tid  = threadIdx.x;
  const int w    = tid >> 6;      // wave = head
  const int lane = tid & 63;
  const int g    = lane >> 4;     // k-group
  const int r    = lane & 15;     // row/col within fragment

  // ---- per-wave weight B-fragments in registers (loaded once) ----
  // Projection y = x @ W^T: B[e][f] = W[f][e]; B-frag elem j = W[f = 32w+16nt+r][e = 32kb+8g+j]
  bfrag wqf[2][4], wkf[2][4], wvf[2][4], wof[2][4];
  float bqv[2], bkv[2], bvv[2], bov[2], gv[2], btv[2];
  #pragma unroll
  for (int nt = 0; nt < 2; ++nt) {
    const int f = 32 * w + 16 * nt + r;
    bqv[nt] = bq[f]; bkv[nt] = bk[f]; bvv[nt] = bv[f];
    bov[nt] = bo[f]; gv[nt] = gam[f]; btv[nt] = bet[f];
    #pragma unroll
    for (int kb = 0; kb < 4; ++kb) {
      const int off = f * 128 + kb * 32 + g * 8;
      wqf[nt][kb] = pack8(*(const float4*)(Wq + off), *(const float4*)(Wq + off + 4));
      wkf[nt][kb] = pack8(*(const float4*)(Wk + off), *(const float4*)(Wk + off + 4));
      wvf[nt][kb] = pack8(*(const float4*)(Wv + off), *(const float4*)(Wv + off + 4));
      wof[nt][kb] = pack8(*(const float4*)(Wo + off), *(const float4*)(Wo + off + 4));
    }
  }

  const f32x4 zf = {0.f, 0.f, 0.f, 0.f};

  for (int it = 0; it < NB_PER_BLK; ++it) {
    const int b = blockIdx.x * NB_PER_BLK + it;
    const float* xg = xin + (size_t)b * 4096;

    // ---- stage x: global f32 -> LDS (f32 padded + bf16 swizzled) ----
    #pragma unroll
    for (int half = 0; half < 2; ++half) {
      const int c = tid + half * 256;          // 512 chunks of 8 f32
      const int row = c >> 4, c16 = c & 15;
      float4 a0 = *(const float4*)(xg + c * 8);
      float4 a1 = *(const float4*)(xg + c * 8 + 4);
      *(float4*)&xf[row * 132 + c16 * 8]     = a0;
      *(float4*)&xf[row * 132 + c16 * 8 + 4] = a1;
      const int idx = row * 128 + (((c16 * 8)) ^ ((row & 7) << 3));  // ushort-index swizzle
      *(bfrag*)&xbf[idx] = pack8(a0, a1);
    }
    __syncthreads();

    // ---- x A-fragments: A[s = r+16mt][e = 32kb+8g+j] ----
    bfrag af[2][4];
    #pragma unroll
    for (int mt = 0; mt < 2; ++mt)
      #pragma unroll
      for (int kb = 0; kb < 4; ++kb)
        af[mt][kb] = *(bfrag*)&xbf[(r + 16 * mt) * 128 + ((kb * 32 + g * 8) ^ ((r & 7) << 3))];

    // ---- Q projection (bias then * 1/sqrt(32)), store row-major [s][d] ----
    {
      f32x4 acc[2][2] = {{zf, zf}, {zf, zf}};
      #pragma unroll
      for (int mt = 0; mt < 2; ++mt)
        #pragma unroll
        for (int nt = 0; nt < 2; ++nt)
          #pragma unroll
          for (int kb = 0; kb < 4; ++kb)
            acc[mt][nt] = __builtin_amdgcn_mfma_f32_16x16x32_bf16(af[mt][kb], wqf[nt][kb], acc[mt][nt], 0, 0, 0);
      #pragma unroll
      for (int mt = 0; mt < 2; ++mt)
        #pragma unroll
        for (int nt = 0; nt < 2; ++nt)
          #pragma unroll
          for (int j = 0; j < 4; ++j) {
            float q = (acc[mt][nt][j] + bqv[nt]) * 0.17677669529663687f;
            qpb[w][(16 * mt + 4 * g + j) * 40 + 16 * nt + r] = f2bf(q);  // D-layout: row=4g+j, col=r
          }
    }
    // ---- K projection ----
    {
      f32x4 acc[2][2] = {{zf, zf}, {zf, zf}};
      #pragma unroll
      for (int mt = 0; mt < 2; ++mt)
        #pragma unroll
        for (int nt = 0; nt < 2; ++nt)
          #pragma unroll
          for (int kb = 0; kb < 4; ++kb)
            acc[mt][nt] = __builtin_amdgcn_mfma_f32_16x16x32_bf16(af[mt][kb], wkf[nt][kb], acc[mt][nt], 0, 0, 0);
      #pragma unroll
      for (int mt = 0; mt < 2; ++mt)
        #pragma unroll
        for (int nt = 0; nt < 2; ++nt)
          #pragma unroll
          for (int j = 0; j < 4; ++j)
            kbuf[w][(16 * mt + 4 * g + j) * 40 + 16 * nt + r] = f2bf(acc[mt][nt][j] + bkv[nt]);
    }
    // ---- V projection -> store V^T ([d][t]); lane's 4 rows become 4 contiguous cols ----
    {
      f32x4 acc[2][2] = {{zf, zf}, {zf, zf}};
      #pragma unroll
      for (int mt = 0; mt < 2; ++mt)
        #pragma unroll
        for (int nt = 0; nt < 2; ++nt)
          #pragma unroll
          for (int kb = 0; kb < 4; ++kb)
            acc[mt][nt] = __builtin_amdgcn_mfma_f32_16x16x32_bf16(af[mt][kb], wvf[nt][kb], acc[mt][nt], 0, 0, 0);
      #pragma unroll
      for (int mt = 0; mt < 2; ++mt)
        #pragma unroll
        for (int nt = 0; nt < 2; ++nt) {
          sh4 v4;
          #pragma unroll
          for (int j = 0; j < 4; ++j) v4[j] = (short)f2bf(acc[mt][nt][j] + bvv[nt]);
          *(sh4*)&vtb[w][(16 * nt + r) * 40 + 16 * mt + 4 * g] = v4;   // VT[d=16nt+r][t=16mt+4g..+3]
        }
    }

    // ---- scores = Q K^T, softmax over t, P overwrites Q buffer ----
    {
      bfrag qa[2], kf[2];
      qa[0] = *(bfrag*)&qpb[w][r * 40 + g * 8];             // A[s=r+16mt][d=8g+j]
      qa[1] = *(bfrag*)&qpb[w][(r + 16) * 40 + g * 8];
      kf[0] = *(bfrag*)&kbuf[w][r * 40 + g * 8];            // B[d][t]: K[t=r+16nt][d=8g+j]
      kf[1] = *(bfrag*)&kbuf[w][(r + 16) * 40 + g * 8];
      f32x4 sacc[2][2];
      #pragma unroll
      for (int mt = 0; mt < 2; ++mt)
        #pragma unroll
        for (int nt = 0; nt < 2; ++nt)
          sacc[mt][nt] = __builtin_amdgcn_mfma_f32_16x16x32_bf16(qa[mt], kf[nt], zf, 0, 0, 0);
      // lane holds scores[s = 16mt+4g+j][t = 16nt+r]; reduce over t = 16 lanes x 2 tiles
      #pragma unroll
      for (int mt = 0; mt < 2; ++mt)
        #pragma unroll
        for (int j = 0; j < 4; ++j) {
          float m = fmaxf(sacc[mt][0][j], sacc[mt][1][j]);
          m = fmaxf(m, __shfl_xor(m, 1));
          m = fmaxf(m, __shfl_xor(m, 2));
          m = fmaxf(m, __shfl_xor(m, 4));
          m = fmaxf(m, __shfl_xor(m, 8));
          float e0 = __expf(sacc[mt][0][j] - m);
          float e1 = __expf(sacc[mt][1][j] - m);
          float s = e0 + e1;
          s += __shfl_xor(s, 1);
          s += __shfl_xor(s, 2);
          s += __shfl_xor(s, 4);
          s += __shfl_xor(s, 8);
          float iv = 1.0f / s;
          const int rowb = (16 * mt + 4 * g + j) * 40;
          qpb[w][rowb + r]      = f2bf(e0 * iv);
          qpb[w][rowb + 16 + r] = f2bf(e1 * iv);
        }
    }
    // ---- ctx = P @ V (B-frag from V^T rows) ----
    {
      bfrag pa[2], vf[2];
      pa[0] = *(bfrag*)&qpb[w][r * 40 + g * 8];             // A[s][t=8g+j]
      pa[1] = *(bfrag*)&qpb[w][(r + 16) * 40 + g * 8];
      vf[0] = *(bfrag*)&vtb[w][r * 40 + g * 8];             // B[t][d]: VT[d=r+16nt][t=8g+j]
      vf[1] = *(bfrag*)&vtb[w][(r + 16) * 40 + g * 8];
      f32x4 cacc[2][2];
      #pragma unroll
      for (int mt = 0; mt < 2; ++mt)
        #pragma unroll
        for (int nt = 0; nt < 2; ++nt)
          cacc[mt][nt] = __builtin_amdgcn_mfma_f32_16x16x32_bf16(pa[mt], vf[nt], zf, 0, 0, 0);
      #pragma unroll
      for (int mt = 0; mt < 2; ++mt)
        #pragma unroll
        for (int nt = 0; nt < 2; ++nt)
          #pragma unroll
          for (int j = 0; j < 4; ++j)
            ctxb[(16 * mt + 4 * g + j) * 136 + 32 * w + 16 * nt + r] = f2bf(cacc[mt][nt][j]);
    }
    __syncthreads();

    // ---- out projection (K=128 over full ctx) + bias + residual ----
    float y[2][2][4];
    {
      bfrag ca[2][4];
      #pragma unroll
      for (int mt = 0; mt < 2; ++mt)
        #pragma unroll
        for (int kb = 0; kb < 4; ++kb)
          ca[mt][kb] = *(bfrag*)&ctxb[(r + 16 * mt) * 136 + kb * 32 + g * 8];
      f32x4 oacc[2][2] = {{zf, zf}, {zf, zf}};
      #pragma unroll
      for (int mt = 0; mt < 2; ++mt)
        #pragma unroll
        for (int nt = 0; nt < 2; ++nt)
          #pragma unroll
          for (int kb = 0; kb < 4; ++kb)
            oacc[mt][nt] = __builtin_amdgcn_mfma_f32_16x16x32_bf16(ca[mt][kb], wof[nt][kb], oacc[mt][nt], 0, 0, 0);
      #pragma unroll
      for (int mt = 0; mt < 2; ++mt)
        #pragma unroll
        for (int nt = 0; nt < 2; ++nt)
          #pragma unroll
          for (int j = 0; j < 4; ++j)
            y[mt][nt][j] = oacc[mt][nt][j] + bov[nt]
                         + xf[(16 * mt + 4 * g + j) * 132 + 32 * w + 16 * nt + r];
    }

    // ---- LayerNorm: per-row (sum, sumsq) partials over this wave's 32 cols ----
    #pragma unroll
    for (int mt = 0; mt < 2; ++mt)
      #pragma unroll
      for (int j = 0; j < 4; ++j) {
        float s1 = y[mt][0][j] + y[mt][1][j];
        float s2 = y[mt][0][j] * y[mt][0][j] + y[mt][1][j] * y[mt][1][j];
        s1 += __shfl_xor(s1, 1); s1 += __shfl_xor(s1, 2); s1 += __shfl_xor(s1, 4); s1 += __shfl_xor(s1, 8);
        s2 += __shfl_xor(s2, 1); s2 += __shfl_xor(s2, 2); s2 += __shfl_xor(s2, 4); s2 += __shfl_xor(s2, 8);
        if (r == 0) {
          redb[w][16 * mt + 4 * g + j][0] = s1;
          redb[w][16 * mt + 4 * g + j][1] = s2;
        }
      }
    __syncthreads();

    // ---- finalize LN + store ----
    float* og = out + (size_t)b * 4096;
    #pragma unroll
    for (int mt = 0; mt < 2; ++mt)
      #pragma unroll
      for (int j = 0; j < 4; ++j) {
        const int srow = 16 * mt + 4 * g + j;
        float s1 = redb[0][srow][0] + redb[1][srow][0] + redb[2][srow][0] + redb[3][srow][0];
        float s2 = redb[0][srow][1] + redb[1][srow][1] + redb[2][srow][1] + redb[3][srow][1];
        float mu   = s1 * 0.0078125f;                 // /128
        float var  = s2 * 0.0078125f - mu * mu;
        float rstd = rsqrtf(var + 1e-5f);
        #pragma unroll
        for (int nt = 0; nt < 2; ++nt) {
          float v = (y[mt][nt][j] - mu) * rstd * gv[nt] + btv[nt];
          og[srow * 128 + 32 * w + 16 * nt + r] = v;
        }
      }
    // next iteration's __syncthreads after staging protects xf/xbf/ctxb/redb reuse
  }
}

extern "C" void kernel_launch(void* const* d_in, const int* in_sizes, int n_in,
                              void* d_out, int out_size, void* d_ws, size_t ws_size,
                              hipStream_t stream) {
  (void)in_sizes; (void)n_in; (void)out_size; (void)d_ws; (void)ws_size;
  const float* xin = (const float*)d_in[0];
  const float* Wq  = (const float*)d_in[1];
  const float* bq  = (const float*)d_in[2];
  const float* Wk  = (const float*)d_in[3];
  const float* bk  = (const float*)d_in[4];
  const float* Wv  = (const float*)d_in[5];
  const float* bv  = (const float*)d_in[6];
  const float* Wo  = (const float*)d_in[7];
  const float* bo  = (const float*)d_in[8];
  const float* gam = (const float*)d_in[9];
  const float* bet = (const float*)d_in[10];
  float* o = (float*)d_out;
  fused_sa_kernel<<<dim3(NBLK), dim3(256), 0, stream>>>(
      xin, Wq, bq, Wk, bk, Wv, bv, Wo, bo, gam, bet, o);
}